// Round 6
// baseline (149.498 us; speedup 1.0000x reference)
//
#include <hip/hip_runtime.h>
#include <hip/hip_cooperative_groups.h>

// B=2, N=1024, Fin=64, Fout=32 — all fp32.
// Degenerate-score GAT, ONE cooperative kernel (512 blocks = 2/CU co-resident):
//   Phase A: projections -> vv (j-major [b][j][f]), p, q1, q2   [round-5 k_proj]
//   grid.sync()                                                  [replaces node gap]
//   Phase B: e[1024]/Z staging + adj.vv dot + fused softmax reductions
//            + epilogue                                          [round-5 k_fused]

#define ALPHA 0.01f
namespace cg = cooperative_groups;

__device__ __forceinline__ float leaky(float x){ return x >= 0.f ? x : ALPHA*x; }

__global__ __launch_bounds__(256, 2) void gat_one(
    const float* __restrict__ inp, const float* __restrict__ kin,
    const float* __restrict__ vin, const float* __restrict__ adj,
    const float* __restrict__ W,   const float* __restrict__ Wk,
    const float* __restrict__ Wv,  const float* __restrict__ a,
    float* __restrict__ vv, float* __restrict__ p,
    float* __restrict__ q1, float* __restrict__ q2,
    float* __restrict__ out)
{
    cg::grid_group grid = cg::this_grid();

    __shared__ float e[1024];            // softmax numerators (shared row)
    __shared__ float accred[4][4][32];   // [wave][row][feature]
    __shared__ float raccred[4][32];     // e.vv partials   [wave][feature]
    __shared__ float vsred[4][32];       // vv sum partials [wave][feature]
    __shared__ float zred[4];

    int tid = threadIdx.x;

    // ---------------- Phase A: projections (verbatim round-5 k_proj) ----
    {
        int lane = tid & 63;
        int f    = lane & 31;
        int h    = lane >> 5;              // c-half selector
        int rl   = tid >> 6;               // 0..3
        int row  = blockIdx.x*4 + rl;      // 0..2047
        const float* xr = inp + row*64 + h*32;
        const float* kr = kin + row*64 + h*32;
        const float* vr = vin + row*64 + h*32;
        const float* Wb  = W  + (h*32)*32 + f;
        const float* Wkb = Wk + (h*32)*32 + f;
        const float* Wvb = Wv + (h*32)*32 + f;
        float ha = 0.f, ka = 0.f, va = 0.f;
        #pragma unroll
        for (int c = 0; c < 32; c++){
            float x = xr[c], k = kr[c], v = vr[c];
            ha += x * Wb [c*32];
            ka += k * Wkb[c*32];
            va += v * Wvb[c*32];
        }
        ha += __shfl_xor(ha, 32);
        ka += __shfl_xor(ka, 32);
        va += __shfl_xor(va, 32);
        if (h == 0) vv[row*32 + f] = va;   // j-major layout
        float a1 = a[f], a2 = a[32+f];
        float pv  = ha*(a1+a2);
        float q1v = ka*a1;
        float q2v = ka*a2;
        #pragma unroll
        for (int m = 16; m; m >>= 1){
            pv  += __shfl_xor(pv , m);
            q1v += __shfl_xor(q1v, m);
            q2v += __shfl_xor(q2v, m);
        }
        if (lane == 0){ p[row] = pv; q1[row] = q1v; q2[row] = q2v; }
    }

    grid.sync();

    // ---------------- Phase B: fused softmax + adj@vv + epilogue --------
    int b   = blockIdx.x & 1;
    int it  = blockIdx.x >> 1;        // 0..255
    int o   = tid & 7;
    int rr  = (tid >> 3) & 3;
    int js  = tid >> 5;               // 0..7
    int w   = tid >> 6;               // wave 0..3
    int i   = it*4 + rr;

    // ---- stage e[1024] + Z (scores bounded ~|2|, exp w/o max-sub safe) ----
    const float* q1b = q1 + b*1024;
    const float* q2b = q2 + b*1024;
    float zsum = 0.f;
    #pragma unroll
    for (int t = 0; t < 4; t++){
        int j  = tid*4 + t;
        float s = leaky(q1b[(2*j) & 1023] + q2b[(2*j+1) & 1023]);
        float ev = __expf(s);
        e[j] = ev;
        zsum += ev;
    }
    #pragma unroll
    for (int m = 32; m; m >>= 1) zsum += __shfl_xor(zsum, m);
    if ((tid & 63) == 0) zred[w] = zsum;
    __syncthreads();

    // ---- main loop: adj.vv + e.vv + Sum vv, 32 iters of 4 j's ----
    const float4* ap = (const float4*)(adj + i*1024 + js*128);
    const float4* ep = (const float4*)(e + js*128);
    const float*  vb = vv + b*32768 + js*128*32 + o*4;
    float4 acc  = make_float4(0.f,0.f,0.f,0.f);
    float4 racc = make_float4(0.f,0.f,0.f,0.f);
    float4 vs   = make_float4(0.f,0.f,0.f,0.f);
    #pragma unroll 4
    for (int m = 0; m < 32; m++){
        float4 a4 = ap[m];
        float4 e4 = ep[m];
        const float* v0p = vb + m*128;
        float4 v0 = *(const float4*)(v0p);
        float4 v1 = *(const float4*)(v0p + 32);
        float4 v2 = *(const float4*)(v0p + 64);
        float4 v3 = *(const float4*)(v0p + 96);
        acc.x += a4.x*v0.x; acc.y += a4.x*v0.y; acc.z += a4.x*v0.z; acc.w += a4.x*v0.w;
        acc.x += a4.y*v1.x; acc.y += a4.y*v1.y; acc.z += a4.y*v1.z; acc.w += a4.y*v1.w;
        acc.x += a4.z*v2.x; acc.y += a4.z*v2.y; acc.z += a4.z*v2.z; acc.w += a4.z*v2.w;
        acc.x += a4.w*v3.x; acc.y += a4.w*v3.y; acc.z += a4.w*v3.z; acc.w += a4.w*v3.w;
        racc.x += e4.x*v0.x; racc.y += e4.x*v0.y; racc.z += e4.x*v0.z; racc.w += e4.x*v0.w;
        racc.x += e4.y*v1.x; racc.y += e4.y*v1.y; racc.z += e4.y*v1.z; racc.w += e4.y*v1.w;
        racc.x += e4.z*v2.x; racc.y += e4.z*v2.y; racc.z += e4.z*v2.z; racc.w += e4.z*v2.w;
        racc.x += e4.w*v3.x; racc.y += e4.w*v3.y; racc.z += e4.w*v3.z; racc.w += e4.w*v3.w;
        vs.x += v0.x + v1.x + v2.x + v3.x;
        vs.y += v0.y + v1.y + v2.y + v3.y;
        vs.z += v0.z + v1.z + v2.z + v3.z;
        vs.w += v0.w + v1.w + v2.w + v3.w;
    }
    // combine js pairs within wave (lane ^ 32)
    acc.x  += __shfl_xor(acc.x, 32);  acc.y  += __shfl_xor(acc.y, 32);
    acc.z  += __shfl_xor(acc.z, 32);  acc.w  += __shfl_xor(acc.w, 32);
    racc.x += __shfl_xor(racc.x, 32); racc.y += __shfl_xor(racc.y, 32);
    racc.z += __shfl_xor(racc.z, 32); racc.w += __shfl_xor(racc.w, 32);
    vs.x   += __shfl_xor(vs.x, 32);   vs.y   += __shfl_xor(vs.y, 32);
    vs.z   += __shfl_xor(vs.z, 32);   vs.w   += __shfl_xor(vs.w, 32);
    if ((tid & 32) == 0){
        accred[w][rr][o*4+0] = acc.x;
        accred[w][rr][o*4+1] = acc.y;
        accred[w][rr][o*4+2] = acc.z;
        accred[w][rr][o*4+3] = acc.w;
        if (rr == 0){
            raccred[w][o*4+0] = racc.x; raccred[w][o*4+1] = racc.y;
            raccred[w][o*4+2] = racc.z; raccred[w][o*4+3] = racc.w;
            vsred[w][o*4+0] = vs.x; vsred[w][o*4+1] = vs.y;
            vsred[w][o*4+2] = vs.z; vsred[w][o*4+3] = vs.w;
        }
    }
    __syncthreads();

    // ---- epilogue: 128 threads = (row rr2, feature f) ----
    if (tid < 128){
        int rr2 = tid >> 5, f = tid & 31;
        float accsum = accred[0][rr2][f] + accred[1][rr2][f]
                     + accred[2][rr2][f] + accred[3][rr2][f];
        int i2 = it*4 + rr2;
        float att;
        if (i2 < 512){
            float vlo = vsred[0][f] + vsred[1][f];   // j <  512
            float vhi = vsred[2][f] + vsred[3][f];   // j >= 512
            float s0 = leaky(p[b*1024 + 2*i2]);
            float s1 = leaky(p[b*1024 + 2*i2 + 1]);
            float e0 = __expf(s0), e1 = __expf(s1);
            att = (e0*vlo + e1*vhi) / (512.f*(e0 + e1));
        } else {
            float rsum = raccred[0][f] + raccred[1][f]
                       + raccred[2][f] + raccred[3][f];
            float Z = zred[0] + zred[1] + zred[2] + zred[3];
            att = rsum / Z;
        }
        out[(b*1024 + i2)*32 + f] = leaky(0.5f*(att + accsum));
    }
}

extern "C" void kernel_launch(void* const* d_in, const int* in_sizes, int n_in,
                              void* d_out, int out_size, void* d_ws, size_t ws_size,
                              hipStream_t stream)
{
    const float* inp = (const float*)d_in[0];
    const float* kin = (const float*)d_in[1];
    const float* vin = (const float*)d_in[2];
    const float* adj = (const float*)d_in[3];
    const float* W   = (const float*)d_in[4];
    const float* Wk  = (const float*)d_in[5];
    const float* Wv  = (const float*)d_in[6];
    const float* a   = (const float*)d_in[7];
    float* out = (float*)d_out;

    float* ws  = (float*)d_ws;
    float* vv  = ws;            // 65536 floats, [b][j][f]
    float* p   = ws + 65536;    // 2048
    float* q1  = ws + 67584;    // 2048
    float* q2  = ws + 69632;    // 2048
    (void)in_sizes; (void)n_in; (void)out_size; (void)ws_size;

    void* kargs[] = {
        (void*)&inp, (void*)&kin, (void*)&vin, (void*)&adj,
        (void*)&W, (void*)&Wk, (void*)&Wv, (void*)&a,
        (void*)&vv, (void*)&p, (void*)&q1, (void*)&q2,
        (void*)&out
    };
    hipLaunchCooperativeKernel((void*)gat_one, dim3(512), dim3(256),
                               kargs, 0, stream);
}

// Round 7
// 86.817 us; speedup vs baseline: 1.7220x; 1.7220x over previous
//
#include <hip/hip_runtime.h>

// B=2, N=1024, Fin=64, Fout=32 — all fp32.
// Degenerate-score GAT, 2 kernels (round-5 structure, block-specialized K2):
//   K1 k_proj : projections -> vv (j-major [b][j][f]), p, q1, q2
//   K2 k_fused: adj.vv dot + fused softmax reductions + epilogue, with
//     block-uniform specialization:
//       it<128  (rows i<512) : acc + vs only — no e staging, no barrier#1
//       it>=128 (rows i>=512): acc + racc + Z only — no vs
// NOTE: cooperative grid.sync measured ~50us on this device (rounds 3/6) —
// two plain graph nodes are strictly cheaper.

#define ALPHA 0.01f

__device__ __forceinline__ float leaky(float x){ return x >= 0.f ? x : ALPHA*x; }

// ---------------- K1: projections + row scalars -------------------------
// 512 blocks x 256 thr; 4 rows/block; wave = 1 row; lane-halves split c.
__global__ __launch_bounds__(256) void k_proj(
    const float* __restrict__ inp, const float* __restrict__ kin,
    const float* __restrict__ vin, const float* __restrict__ W,
    const float* __restrict__ Wk,  const float* __restrict__ Wv,
    const float* __restrict__ a,
    float* __restrict__ vv, float* __restrict__ p,
    float* __restrict__ q1, float* __restrict__ q2)
{
    int tid  = threadIdx.x;
    int lane = tid & 63;
    int f    = lane & 31;
    int h    = lane >> 5;          // c-half selector
    int rl   = tid >> 6;           // 0..3
    int row  = blockIdx.x*4 + rl;  // 0..2047
    const float* xr = inp + row*64 + h*32;
    const float* kr = kin + row*64 + h*32;
    const float* vr = vin + row*64 + h*32;
    const float* Wb  = W  + (h*32)*32 + f;
    const float* Wkb = Wk + (h*32)*32 + f;
    const float* Wvb = Wv + (h*32)*32 + f;
    float ha = 0.f, ka = 0.f, va = 0.f;
    #pragma unroll
    for (int c = 0; c < 32; c++){
        float x = xr[c], k = kr[c], v = vr[c];
        ha += x * Wb [c*32];
        ka += k * Wkb[c*32];
        va += v * Wvb[c*32];
    }
    ha += __shfl_xor(ha, 32);
    ka += __shfl_xor(ka, 32);
    va += __shfl_xor(va, 32);
    if (h == 0) vv[row*32 + f] = va;        // j-major layout
    float a1 = a[f], a2 = a[32+f];
    float pv  = ha*(a1+a2);
    float q1v = ka*a1;
    float q2v = ka*a2;
    #pragma unroll
    for (int m = 16; m; m >>= 1){
        pv  += __shfl_xor(pv , m);
        q1v += __shfl_xor(q1v, m);
        q2v += __shfl_xor(q2v, m);
    }
    if (lane == 0){ p[row] = pv; q1[row] = q1v; q2[row] = q2v; }
}

// ---------------- K2: fused softmax + adj@vv + epilogue -----------------
// 512 blocks x 256 thr. block = (batch b, 4 rows). thread = (o, rr, js):
//   o  = tid&7        feature quad (f = o*4..o*4+3)
//   rr = (tid>>3)&3   row within block
//   js = tid>>5       j-slice of 128 (waves 0-1: j<512, waves 2-3: j>=512)
__global__ __launch_bounds__(256) void k_fused(
    const float* __restrict__ adj, const float* __restrict__ vv,
    const float* __restrict__ p,   const float* __restrict__ q1,
    const float* __restrict__ q2,  float* __restrict__ out)
{
    __shared__ float e[1024];            // hi-blocks only
    __shared__ float accred[4][4][32];   // [wave][row][feature]
    __shared__ float xred[4][32];        // lo: vs partials / hi: racc partials
    __shared__ float zred[4];            // hi-blocks only

    int tid = threadIdx.x;
    int b   = blockIdx.x & 1;
    int it  = blockIdx.x >> 1;        // 0..255
    int o   = tid & 7;
    int rr  = (tid >> 3) & 3;
    int js  = tid >> 5;               // 0..7
    int w   = tid >> 6;               // wave 0..3
    int i   = it*4 + rr;
    bool hi = (it >= 128);            // block-uniform: rows i >= 512

    const float4* ap = (const float4*)(adj + i*1024 + js*128);
    const float*  vb = vv + b*32768 + js*128*32 + o*4;
    float4 acc = make_float4(0.f,0.f,0.f,0.f);
    float4 aux = make_float4(0.f,0.f,0.f,0.f);   // lo: vs / hi: racc

    if (hi){
        // ---- stage e[1024] + Z (scores ~|2|, exp w/o max-sub safe) ----
        const float* q1b = q1 + b*1024;
        const float* q2b = q2 + b*1024;
        float zsum = 0.f;
        #pragma unroll
        for (int t = 0; t < 4; t++){
            int j  = tid*4 + t;
            float s = leaky(q1b[(2*j) & 1023] + q2b[(2*j+1) & 1023]);
            float ev = __expf(s);
            e[j] = ev;
            zsum += ev;
        }
        #pragma unroll
        for (int m = 32; m; m >>= 1) zsum += __shfl_xor(zsum, m);
        if ((tid & 63) == 0) zred[w] = zsum;
        __syncthreads();

        const float4* ep = (const float4*)(e + js*128);
        #pragma unroll 4
        for (int m = 0; m < 32; m++){
            float4 a4 = ap[m];
            float4 e4 = ep[m];
            const float* v0p = vb + m*128;
            float4 v0 = *(const float4*)(v0p);
            float4 v1 = *(const float4*)(v0p + 32);
            float4 v2 = *(const float4*)(v0p + 64);
            float4 v3 = *(const float4*)(v0p + 96);
            acc.x += a4.x*v0.x; acc.y += a4.x*v0.y; acc.z += a4.x*v0.z; acc.w += a4.x*v0.w;
            acc.x += a4.y*v1.x; acc.y += a4.y*v1.y; acc.z += a4.y*v1.z; acc.w += a4.y*v1.w;
            acc.x += a4.z*v2.x; acc.y += a4.z*v2.y; acc.z += a4.z*v2.z; acc.w += a4.z*v2.w;
            acc.x += a4.w*v3.x; acc.y += a4.w*v3.y; acc.z += a4.w*v3.z; acc.w += a4.w*v3.w;
            aux.x += e4.x*v0.x; aux.y += e4.x*v0.y; aux.z += e4.x*v0.z; aux.w += e4.x*v0.w;
            aux.x += e4.y*v1.x; aux.y += e4.y*v1.y; aux.z += e4.y*v1.z; aux.w += e4.y*v1.w;
            aux.x += e4.z*v2.x; aux.y += e4.z*v2.y; aux.z += e4.z*v2.z; aux.w += e4.z*v2.w;
            aux.x += e4.w*v3.x; aux.y += e4.w*v3.y; aux.z += e4.w*v3.z; aux.w += e4.w*v3.w;
        }
    } else {
        // ---- lo: acc + column-sums of vv only ----
        #pragma unroll 4
        for (int m = 0; m < 32; m++){
            float4 a4 = ap[m];
            const float* v0p = vb + m*128;
            float4 v0 = *(const float4*)(v0p);
            float4 v1 = *(const float4*)(v0p + 32);
            float4 v2 = *(const float4*)(v0p + 64);
            float4 v3 = *(const float4*)(v0p + 96);
            acc.x += a4.x*v0.x; acc.y += a4.x*v0.y; acc.z += a4.x*v0.z; acc.w += a4.x*v0.w;
            acc.x += a4.y*v1.x; acc.y += a4.y*v1.y; acc.z += a4.y*v1.z; acc.w += a4.y*v1.w;
            acc.x += a4.z*v2.x; acc.y += a4.z*v2.y; acc.z += a4.z*v2.z; acc.w += a4.z*v2.w;
            acc.x += a4.w*v3.x; acc.y += a4.w*v3.y; acc.z += a4.w*v3.z; acc.w += a4.w*v3.w;
            aux.x += v0.x + v1.x + v2.x + v3.x;
            aux.y += v0.y + v1.y + v2.y + v3.y;
            aux.z += v0.z + v1.z + v2.z + v3.z;
            aux.w += v0.w + v1.w + v2.w + v3.w;
        }
    }

    // combine js pairs within wave (lane ^ 32)
    acc.x += __shfl_xor(acc.x, 32); acc.y += __shfl_xor(acc.y, 32);
    acc.z += __shfl_xor(acc.z, 32); acc.w += __shfl_xor(acc.w, 32);
    aux.x += __shfl_xor(aux.x, 32); aux.y += __shfl_xor(aux.y, 32);
    aux.z += __shfl_xor(aux.z, 32); aux.w += __shfl_xor(aux.w, 32);
    if ((tid & 32) == 0){
        accred[w][rr][o*4+0] = acc.x;
        accred[w][rr][o*4+1] = acc.y;
        accred[w][rr][o*4+2] = acc.z;
        accred[w][rr][o*4+3] = acc.w;
        if (rr == 0){
            xred[w][o*4+0] = aux.x; xred[w][o*4+1] = aux.y;
            xred[w][o*4+2] = aux.z; xred[w][o*4+3] = aux.w;
        }
    }
    __syncthreads();

    // ---- epilogue: 128 threads = (row rr2, feature f) ----
    if (tid < 128){
        int rr2 = tid >> 5, f = tid & 31;
        float accsum = accred[0][rr2][f] + accred[1][rr2][f]
                     + accred[2][rr2][f] + accred[3][rr2][f];
        int i2 = it*4 + rr2;
        float att;
        if (!hi){
            float vlo = xred[0][f] + xred[1][f];   // j <  512
            float vhi = xred[2][f] + xred[3][f];   // j >= 512
            float s0 = leaky(p[b*1024 + 2*i2]);
            float s1 = leaky(p[b*1024 + 2*i2 + 1]);
            float e0 = __expf(s0), e1 = __expf(s1);
            att = (e0*vlo + e1*vhi) / (512.f*(e0 + e1));
        } else {
            float rsum = xred[0][f] + xred[1][f] + xred[2][f] + xred[3][f];
            float Z = zred[0] + zred[1] + zred[2] + zred[3];
            att = rsum / Z;
        }
        out[(b*1024 + i2)*32 + f] = leaky(0.5f*(att + accsum));
    }
}

extern "C" void kernel_launch(void* const* d_in, const int* in_sizes, int n_in,
                              void* d_out, int out_size, void* d_ws, size_t ws_size,
                              hipStream_t stream)
{
    const float* inp = (const float*)d_in[0];
    const float* kin = (const float*)d_in[1];
    const float* vin = (const float*)d_in[2];
    const float* adj = (const float*)d_in[3];
    const float* W   = (const float*)d_in[4];
    const float* Wk  = (const float*)d_in[5];
    const float* Wv  = (const float*)d_in[6];
    const float* a   = (const float*)d_in[7];
    float* out = (float*)d_out;

    float* ws  = (float*)d_ws;
    float* vv  = ws;            // 65536 floats, [b][j][f]
    float* p   = ws + 65536;    // 2048
    float* q1  = ws + 67584;    // 2048
    float* q2  = ws + 69632;    // 2048
    (void)in_sizes; (void)n_in; (void)out_size; (void)ws_size;

    hipLaunchKernelGGL(k_proj, dim3(512), dim3(256), 0, stream,
                       inp, kin, vin, W, Wk, Wv, a, vv, p, q1, q2);
    hipLaunchKernelGGL(k_fused, dim3(512), dim3(256), 0, stream,
                       adj, vv, p, q1, q2, out);
}